// Round 19
// baseline (129.436 us; speedup 1.0000x reference)
//
#include <hip/hip_runtime.h>
#include <stdint.h>

#define M_DIM 8192
#define K_DIM 4096
#define N_DIM 4096

using i32x4 = __attribute__((ext_vector_type(4))) int;
using i32x8 = __attribute__((ext_vector_type(8))) int;
using f32x16 = __attribute__((ext_vector_type(16))) float;

typedef const __attribute__((address_space(1))) void g_void;
typedef __attribute__((address_space(3))) void lds_void;

__device__ __forceinline__ void gload_lds16(const void* g, void* l) {
  __builtin_amdgcn_global_load_lds((g_void*)g, (lds_void*)l, 16, 0, 0);
}

__device__ __forceinline__ void barrier_raw() {
  asm volatile("" ::: "memory");
  __builtin_amdgcn_s_barrier();
  asm volatile("" ::: "memory");
}

// fp4 e2m1: +1 = 0x2 (1.0), -1 = 0xA, 0 = 0x0
__device__ __forceinline__ unsigned code4(float v) {
  return v > 0.f ? 0x2u : (v < 0.f ? 0xAu : 0x0u);
}

// ---- pack x: fp32 [M][K] -> GEMM-ready fp4 [g=M/32][t=K/128][kc=4][row=32]x16B
__global__ void pack_x4_kernel(const float* __restrict__ in,
                               uint8_t* __restrict__ out) {
  __shared__ __align__(16) uint16_t cds[32 * 264];
  int g = blockIdx.x;
  int tq = blockIdx.y;
  int tid = threadIdx.x;
#pragma unroll
  for (int i = 0; i < 32; ++i) {
    int flat = tid + 256 * i;
    int row = flat >> 8;
    int c4 = flat & 255;
    const float4 v = *reinterpret_cast<const float4*>(
        in + (long)(g * 32 + row) * K_DIM + tq * 1024 + c4 * 4);
    unsigned u = code4(v.x) | (code4(v.y) << 4) | (code4(v.z) << 8) |
                 (code4(v.w) << 12);
    cds[row * 264 + c4] = (uint16_t)u;
  }
  __syncthreads();
#pragma unroll
  for (int j = 0; j < 4; ++j) {
    int u = tid + 256 * j;
    int tl = u >> 7;
    int kc = (u >> 5) & 3;
    int row = u & 31;
    i32x4 val = *reinterpret_cast<const i32x4*>(&cds[row * 264 + tl * 32 + kc * 8]);
    int t = tq * 8 + tl;
    long o = ((((long)g * 32 + t) * 4 + kc) * 32 + row) * 16;
    *reinterpret_cast<i32x4*>(out + o) = val;
  }
}

// ---- pack w: fp32 [K][N] -> GEMM-ready fp4 W^T [g=N/32][t][kc][row32]x16B
__global__ void pack_wt4_kernel(const float* __restrict__ w,
                                uint8_t* __restrict__ out) {
  __shared__ __align__(16) uint8_t tile[64 * 144];
  int n0 = blockIdx.x * 64;
  int k0 = blockIdx.y * 128;
  int tid = threadIdx.x;
#pragma unroll
  for (int i = 0; i < 32; ++i) {
    int flat = tid + 256 * i;
    int r = flat >> 6;
    int c = flat & 63;
    tile[c * 144 + r] = (uint8_t)code4(w[(long)(k0 + r) * N_DIM + n0 + c]);
  }
  __syncthreads();
  int rg = tid >> 7, kc = (tid >> 5) & 3, row = tid & 31;
  const unsigned* sp =
      reinterpret_cast<const unsigned*>(&tile[(rg * 32 + row) * 144 + kc * 32]);
  i32x4 val;
#pragma unroll
  for (int d = 0; d < 4; ++d) {
    unsigned s0 = sp[2 * d], s1 = sp[2 * d + 1];
    unsigned t0 = s0 & 0x0F0F0F0Fu, t1 = s1 & 0x0F0F0F0Fu;
    unsigned p = (t0 | (t0 >> 4)) & 0x00FF00FFu;
    unsigned q = (t1 | (t1 >> 4)) & 0x00FF00FFu;
    val[d] = (int)((p & 0xFFu) | ((p >> 8) & 0xFF00u) | ((q & 0xFFu) << 16) |
                   ((q >> 16) << 24));
  }
  int g = (n0 >> 5) + rg;
  int t = k0 >> 7;
  long o = ((((long)g * 32 + t) * 4 + kc) * 32 + row) * 16;
  *reinterpret_cast<i32x4*>(out + o) = val;
}

// ---- MX-fp4 GEMM: R18 base (128x256, 4 waves, 2 async blocks/CU, A-LDS,
//      B-direct) + HALVED SYNC RATE: one vmcnt(0)+barrier per 2 K-tiles.
// R18 residual diagnosis: ~1300 cyc/tile of correlated convoy stall around
// the per-tile gate (both blocks drift into phase via pipe contention).
// Pair schedule (tiles t,t+1 between gates; counted lgkm pipelines reads):
//   issue {B,A}(t+2),(t+3); reads(t) x8
//   lgkm(4)->h0(t); reads(t+1) x8 under h1; lgkm(8)->h1(t)
//   lgkm(4)->h0(t+1); lgkm(0)->h1(t+1); vmcnt(0)+barrier
// A-ring 4 x 8 KB slots; B 4 rotating reg sets.
// WAR: slots (t+2),(t+3) last read one gate ago, ds_reads retired by that
// pair's lgkm(0) before its barrier.
__device__ __forceinline__ i32x8 lo8(i32x4 r) {
  return __builtin_shufflevector(r, r, 0, 1, 2, 3, -1, -1, -1, -1);
}

#define SCALE1 0x7f7f7f7f  // E8M0 1.0 in every byte

#define MFMA8(AV, BV0, BV1)                                                 \
  do {                                                                      \
    __builtin_amdgcn_sched_barrier(0);                                      \
    __builtin_amdgcn_s_setprio(1);                                          \
    _Pragma("unroll") for (int mi = 0; mi < 4; ++mi) {                      \
      acc[mi][0] = __builtin_amdgcn_mfma_scale_f32_32x32x64_f8f6f4(         \
          lo8(AV[mi]), lo8(BV0), acc[mi][0], 4, 4, 0, SCALE1, 0, SCALE1);   \
      acc[mi][1] = __builtin_amdgcn_mfma_scale_f32_32x32x64_f8f6f4(         \
          lo8(AV[mi]), lo8(BV1), acc[mi][1], 4, 4, 0, SCALE1, 0, SCALE1);   \
    }                                                                       \
    __builtin_amdgcn_s_setprio(0);                                          \
  } while (0)

template <bool ISSUE, bool GATE, int CUR>
__device__ __forceinline__ void pair_step(
    int t, const uint8_t* __restrict__ gA, const uint8_t* __restrict__ gB,
    int dstA, uint8_t* lds, int aRd, i32x4 (&bC0)[4], i32x4 (&bC1)[4],
    i32x4 (&bN0)[4], i32x4 (&bN1)[4], f32x16 (&acc)[4][2]) {
  // issue next-pair prefetch: B(t+2)->bN0, B(t+3)->bN1, A(t+2),(t+3)->ring
  if (ISSUE) {
    long k2 = (long)(t + 2) * 2048, k3 = (long)(t + 3) * 2048;
    bN0[0] = *reinterpret_cast<const i32x4*>(gB + k2);
    bN0[1] = *reinterpret_cast<const i32x4*>(gB + 65536 + k2);
    bN0[2] = *reinterpret_cast<const i32x4*>(gB + k2 + 1024);
    bN0[3] = *reinterpret_cast<const i32x4*>(gB + 65536 + k2 + 1024);
    bN1[0] = *reinterpret_cast<const i32x4*>(gB + k3);
    bN1[1] = *reinterpret_cast<const i32x4*>(gB + 65536 + k3);
    bN1[2] = *reinterpret_cast<const i32x4*>(gB + k3 + 1024);
    bN1[3] = *reinterpret_cast<const i32x4*>(gB + 65536 + k3 + 1024);
    uint8_t* nb0 = lds + ((CUR + 2) & 3) * 8192;
    uint8_t* nb1 = lds + ((CUR + 3) & 3) * 8192;
    gload_lds16(gA + k2, nb0 + dstA);
    gload_lds16(gA + k2 + 1024, nb0 + dstA + 1024);
    gload_lds16(gA + k3, nb1 + dstA);
    gload_lds16(gA + k3 + 1024, nb1 + dstA + 1024);
  }
  const uint8_t* buf0 = lds + CUR * 8192;
  const uint8_t* buf1 = lds + ((CUR + 1) & 3) * 8192;
  i32x4 a0[4], a1[4], c0[4], c1[4];
  // reads of tile t (h0 then h1)
#pragma unroll
  for (int mi = 0; mi < 4; ++mi)
    a0[mi] = *reinterpret_cast<const i32x4*>(buf0 + aRd + mi * 2048);
#pragma unroll
  for (int mi = 0; mi < 4; ++mi)
    a1[mi] = *reinterpret_cast<const i32x4*>(buf0 + aRd + mi * 2048 + 1024);
  asm volatile("s_waitcnt lgkmcnt(4)" ::: "memory");  // a0 ready
  MFMA8(a0, bC0[0], bC0[1]);                          // h0(t); a1 drains under
  // reads of tile t+1 issue here -> drain under h1(t)
#pragma unroll
  for (int mi = 0; mi < 4; ++mi)
    c0[mi] = *reinterpret_cast<const i32x4*>(buf1 + aRd + mi * 2048);
#pragma unroll
  for (int mi = 0; mi < 4; ++mi)
    c1[mi] = *reinterpret_cast<const i32x4*>(buf1 + aRd + mi * 2048 + 1024);
  asm volatile("s_waitcnt lgkmcnt(8)" ::: "memory");  // retires exactly a1
  MFMA8(a1, bC0[2], bC0[3]);                          // h1(t)
  asm volatile("s_waitcnt lgkmcnt(4)" ::: "memory");  // c0 ready
  MFMA8(c0, bC1[0], bC1[1]);                          // h0(t+1)
  asm volatile("s_waitcnt lgkmcnt(0)" ::: "memory");  // c1 ready
  MFMA8(c1, bC1[2], bC1[3]);                          // h1(t+1)
  if (GATE) {
    asm volatile("s_waitcnt vmcnt(0)" ::: "memory");  // next pair staged
    barrier_raw();
  }
}

__global__ __launch_bounds__(256, 2) void gemm_fp4_kernel(
    const uint8_t* __restrict__ A, const uint8_t* __restrict__ B,
    float* __restrict__ C) {
  __shared__ __align__(16) uint8_t lds[4 * 8192];  // 32 KiB, A-only 4-ring

  // L2-locality XCD map: bijective over 64bm x 16bn, rectangle per XCD
  int bid = blockIdx.x;
  int xcd = bid & 7;
  int i = bid >> 3;                        // 0..127
  int bn = (i & 7) + ((xcd & 1) << 3);     // 0..15
  int bm = (i >> 3) + ((xcd >> 1) << 4);   // 0..63

  int tid = threadIdx.x;
  int wid = tid >> 6;  // 0..3 = N quarter; wave owns all 128 M-rows
  int lane = tid & 63;

  const uint8_t* gA = A + (long)(bm * 4 + wid) * 65536 + lane * 16;
  const uint8_t* gB = B + (long)(bn * 8 + 2 * wid) * 65536 + lane * 16;
  int dstA = wid * 2048;  // 4 waves x 2KB = 8KB slot
  int aRd = lane * 16;

  i32x4 bsA[4], bsB[4], bsC[4], bsD[4];
  f32x16 acc[4][2] = {};

  // prologue: B(0)->bsA, B(1)->bsB; stage A(0),A(1) into slots 0,1
  bsA[0] = *reinterpret_cast<const i32x4*>(gB);
  bsA[1] = *reinterpret_cast<const i32x4*>(gB + 65536);
  bsA[2] = *reinterpret_cast<const i32x4*>(gB + 1024);
  bsA[3] = *reinterpret_cast<const i32x4*>(gB + 65536 + 1024);
  bsB[0] = *reinterpret_cast<const i32x4*>(gB + 2048);
  bsB[1] = *reinterpret_cast<const i32x4*>(gB + 65536 + 2048);
  bsB[2] = *reinterpret_cast<const i32x4*>(gB + 3072);
  bsB[3] = *reinterpret_cast<const i32x4*>(gB + 65536 + 3072);
  gload_lds16(gA, lds + dstA);
  gload_lds16(gA + 1024, lds + dstA + 1024);
  gload_lds16(gA + 2048, lds + 8192 + dstA);
  gload_lds16(gA + 3072, lds + 8192 + dstA + 1024);
  asm volatile("s_waitcnt vmcnt(0)" ::: "memory");
  barrier_raw();

  // 16 pairs: even pair -> slots 0,1 consume bsA,bsB load bsC,bsD;
  //           odd pair  -> slots 2,3 consume bsC,bsD load bsA,bsB.
#pragma unroll 1
  for (int k = 0; k < 7; ++k) {
    int t = k * 4;  // pairs 2k, 2k+1
    pair_step<true, true, 0>(t, gA, gB, dstA, lds, aRd, bsA, bsB, bsC, bsD, acc);
    pair_step<true, true, 2>(t + 2, gA, gB, dstA, lds, aRd, bsC, bsD, bsA, bsB, acc);
  }
  pair_step<true, true, 0>(28, gA, gB, dstA, lds, aRd, bsA, bsB, bsC, bsD, acc);
  pair_step<false, false, 2>(30, gA, gB, dstA, lds, aRd, bsC, bsD, bsA, bsB, acc);

  // C/D 32x32 layout: col = lane&31, row = (reg&3) + 8*(reg>>2) + 4*(lane>>5)
  long row0 = (long)bm * 128 + ((lane >> 5) << 2);
  long col0 = (long)bn * 256 + wid * 64 + (lane & 31);
#pragma unroll
  for (int mi = 0; mi < 4; ++mi)
#pragma unroll
    for (int ni = 0; ni < 2; ++ni)
#pragma unroll
      for (int r = 0; r < 16; ++r) {
        long row = row0 + mi * 32 + (r & 3) + ((r >> 2) << 3);
        C[row * N_DIM + col0 + ni * 32] = acc[mi][ni][r];
      }
}

extern "C" void kernel_launch(void* const* d_in, const int* in_sizes, int n_in,
                              void* d_out, int out_size, void* d_ws, size_t ws_size,
                              hipStream_t stream) {
  const float* x = (const float*)d_in[0];
  const float* w = (const float*)d_in[1];
  float* out = (float*)d_out;

  uint8_t* x4 = (uint8_t*)d_ws;                     // 16 MB GEMM-ready A
  uint8_t* w4t = x4 + (size_t)M_DIM * (K_DIM / 2);  // 8 MB GEMM-ready W^T

  pack_x4_kernel<<<dim3(M_DIM / 32, 4), 256, 0, stream>>>(x, x4);
  pack_wt4_kernel<<<dim3(N_DIM / 64, K_DIM / 128), 256, 0, stream>>>(w, w4t);
  gemm_fp4_kernel<<<1024, 256, 0, stream>>>(x4, w4t, out);
}

// Round 20
// 124.344 us; speedup vs baseline: 1.0410x; 1.0410x over previous
//
#include <hip/hip_runtime.h>
#include <stdint.h>

#define M_DIM 8192
#define K_DIM 4096
#define N_DIM 4096

using i32x4 = __attribute__((ext_vector_type(4))) int;
using i32x8 = __attribute__((ext_vector_type(8))) int;
using f32x16 = __attribute__((ext_vector_type(16))) float;

typedef const __attribute__((address_space(1))) void g_void;
typedef __attribute__((address_space(3))) void lds_void;

__device__ __forceinline__ void gload_lds16(const void* g, void* l) {
  __builtin_amdgcn_global_load_lds((g_void*)g, (lds_void*)l, 16, 0, 0);
}

__device__ __forceinline__ void barrier_raw() {
  asm volatile("" ::: "memory");
  __builtin_amdgcn_s_barrier();
  asm volatile("" ::: "memory");
}

// fp4 e2m1: +1 = 0x2 (1.0), -1 = 0xA, 0 = 0x0
__device__ __forceinline__ unsigned code4(float v) {
  return v > 0.f ? 0x2u : (v < 0.f ? 0xAu : 0x0u);
}

// ---- pack x: fp32 [M][K] -> GEMM-ready fp4 [g=M/32][t=K/128][kc=4][row=32]x16B
__global__ void pack_x4_kernel(const float* __restrict__ in,
                               uint8_t* __restrict__ out) {
  __shared__ __align__(16) uint16_t cds[32 * 264];
  int g = blockIdx.x;
  int tq = blockIdx.y;
  int tid = threadIdx.x;
#pragma unroll
  for (int i = 0; i < 32; ++i) {
    int flat = tid + 256 * i;
    int row = flat >> 8;
    int c4 = flat & 255;
    const float4 v = *reinterpret_cast<const float4*>(
        in + (long)(g * 32 + row) * K_DIM + tq * 1024 + c4 * 4);
    unsigned u = code4(v.x) | (code4(v.y) << 4) | (code4(v.z) << 8) |
                 (code4(v.w) << 12);
    cds[row * 264 + c4] = (uint16_t)u;
  }
  __syncthreads();
#pragma unroll
  for (int j = 0; j < 4; ++j) {
    int u = tid + 256 * j;
    int tl = u >> 7;
    int kc = (u >> 5) & 3;
    int row = u & 31;
    i32x4 val = *reinterpret_cast<const i32x4*>(&cds[row * 264 + tl * 32 + kc * 8]);
    int t = tq * 8 + tl;
    long o = ((((long)g * 32 + t) * 4 + kc) * 32 + row) * 16;
    *reinterpret_cast<i32x4*>(out + o) = val;
  }
}

// ---- pack w: fp32 [K][N] -> GEMM-ready fp4 W^T [g=N/32][t][kc][row32]x16B
__global__ void pack_wt4_kernel(const float* __restrict__ w,
                                uint8_t* __restrict__ out) {
  __shared__ __align__(16) uint8_t tile[64 * 144];
  int n0 = blockIdx.x * 64;
  int k0 = blockIdx.y * 128;
  int tid = threadIdx.x;
#pragma unroll
  for (int i = 0; i < 32; ++i) {
    int flat = tid + 256 * i;
    int r = flat >> 6;
    int c = flat & 63;
    tile[c * 144 + r] = (uint8_t)code4(w[(long)(k0 + r) * N_DIM + n0 + c]);
  }
  __syncthreads();
  int rg = tid >> 7, kc = (tid >> 5) & 3, row = tid & 31;
  const unsigned* sp =
      reinterpret_cast<const unsigned*>(&tile[(rg * 32 + row) * 144 + kc * 32]);
  i32x4 val;
#pragma unroll
  for (int d = 0; d < 4; ++d) {
    unsigned s0 = sp[2 * d], s1 = sp[2 * d + 1];
    unsigned t0 = s0 & 0x0F0F0F0Fu, t1 = s1 & 0x0F0F0F0Fu;
    unsigned p = (t0 | (t0 >> 4)) & 0x00FF00FFu;
    unsigned q = (t1 | (t1 >> 4)) & 0x00FF00FFu;
    val[d] = (int)((p & 0xFFu) | ((p >> 8) & 0xFF00u) | ((q & 0xFFu) << 16) |
                   ((q >> 16) << 24));
  }
  int g = (n0 >> 5) + rg;
  int t = k0 >> 7;
  long o = ((((long)g * 32 + t) * 4 + kc) * 32 + row) * 16;
  *reinterpret_cast<i32x4*>(out + o) = val;
}

// ---- MX-fp4 GEMM: 128x256 tile, 4 waves, 2 ASYNC blocks/CU ----
// R16 configuration, restored (best measured: 124.5 us total, absmax 0).
// Mechanism: two independent blocks per CU provide phase diversity that
// covers per-tile gate/read stalls (R15's lockstep limitation); staging is
// fully coalesced via the GEMM-ready workspace layout (R14); rectangular
// XCD mapping keeps the L2 hot set small (R12).
// vmcnt ledger: stage(t+2) at top (6 loads); gate vmcnt(6) = t+1 landed,
// t+2 in flight. WAR: slot (t+2)%3=(t-1)%3, reads retired at t-1's
// lgkm(0) before its end barrier.
__device__ __forceinline__ i32x8 lo8(i32x4 r) {
  return __builtin_shufflevector(r, r, 0, 1, 2, 3, -1, -1, -1, -1);
}

#define SCALE1 0x7f7f7f7f  // E8M0 1.0 in every byte

template <int VM, bool ISSUE, int CUR>
__device__ __forceinline__ void tile_step(
    int t, const uint8_t* __restrict__ gA, const uint8_t* __restrict__ gB0,
    const uint8_t* __restrict__ gB1, int dstA, int dstB, uint8_t* lds,
    int aRd, int bRd, f32x16 (&acc)[4][2]) {
  const uint8_t* buf = lds + CUR * 24576;
  constexpr int SN = (CUR + 2) % 3;
  if (ISSUE) {
    long kn = (long)(t + 2) * 2048;
    uint8_t* nbuf = lds + SN * 24576;
    gload_lds16(gA + kn, nbuf + dstA);
    gload_lds16(gA + kn + 1024, nbuf + dstA + 1024);
    gload_lds16(gB0 + kn, nbuf + dstB);
    gload_lds16(gB0 + kn + 1024, nbuf + dstB + 1024);
    gload_lds16(gB1 + kn, nbuf + dstB + 2048);
    gload_lds16(gB1 + kn + 1024, nbuf + dstB + 3072);
  }
  // 12 frag reads, h0 first (lgkm(6) retires exactly h0)
  i32x4 a0[4], b0[2], a1[4], b1[2];
#pragma unroll
  for (int mi = 0; mi < 4; ++mi)
    a0[mi] = *reinterpret_cast<const i32x4*>(buf + aRd + mi * 2048);
#pragma unroll
  for (int ni = 0; ni < 2; ++ni)
    b0[ni] = *reinterpret_cast<const i32x4*>(buf + bRd + ni * 2048);
#pragma unroll
  for (int mi = 0; mi < 4; ++mi)
    a1[mi] = *reinterpret_cast<const i32x4*>(buf + aRd + mi * 2048 + 1024);
#pragma unroll
  for (int ni = 0; ni < 2; ++ni)
    b1[ni] = *reinterpret_cast<const i32x4*>(buf + bRd + ni * 2048 + 1024);
  asm volatile("s_waitcnt lgkmcnt(6)" ::: "memory");
  __builtin_amdgcn_sched_barrier(0);
  __builtin_amdgcn_s_setprio(1);
#pragma unroll
  for (int mi = 0; mi < 4; ++mi)
#pragma unroll
    for (int ni = 0; ni < 2; ++ni)
      acc[mi][ni] = __builtin_amdgcn_mfma_scale_f32_32x32x64_f8f6f4(
          lo8(a0[mi]), lo8(b0[ni]), acc[mi][ni], 4, 4, 0, SCALE1, 0, SCALE1);
  __builtin_amdgcn_s_setprio(0);
  asm volatile("s_waitcnt lgkmcnt(0)" ::: "memory");
  __builtin_amdgcn_sched_barrier(0);
  __builtin_amdgcn_s_setprio(1);
#pragma unroll
  for (int mi = 0; mi < 4; ++mi)
#pragma unroll
    for (int ni = 0; ni < 2; ++ni)
      acc[mi][ni] = __builtin_amdgcn_mfma_scale_f32_32x32x64_f8f6f4(
          lo8(a1[mi]), lo8(b1[ni]), acc[mi][ni], 4, 4, 0, SCALE1, 0, SCALE1);
  __builtin_amdgcn_s_setprio(0);
  if (VM >= 0) {
    if (VM == 6) asm volatile("s_waitcnt vmcnt(6)" ::: "memory");
    else asm volatile("s_waitcnt vmcnt(0)" ::: "memory");
    barrier_raw();
  }
}

__global__ __launch_bounds__(256, 2) void gemm_fp4_kernel(
    const uint8_t* __restrict__ A, const uint8_t* __restrict__ B,
    float* __restrict__ C) {
  __shared__ __align__(16) uint8_t lds[3 * 24576];  // 72 KiB

  // L2-locality XCD map: bijective over 64bm x 16bn, rectangle per XCD
  int bid = blockIdx.x;
  int xcd = bid & 7;
  int i = bid >> 3;                        // 0..127
  int bn = (i & 7) + ((xcd & 1) << 3);     // 0..15
  int bm = (i >> 3) + ((xcd >> 1) << 4);   // 0..63

  int tid = threadIdx.x;
  int wid = tid >> 6;  // 0..3 = wc (N quarter); wave owns all 128 M-rows
  int lane = tid & 63;

  // staging bases (GEMM-ready layout, fully contiguous per issue)
  const uint8_t* gA = A + (long)(bm * 4 + wid) * 65536 + lane * 16;
  const uint8_t* gB0 = B + (long)(bn * 8 + 2 * wid) * 65536 + lane * 16;
  const uint8_t* gB1 = gB0 + 65536;
  int dstA = wid * 2048;           // A region [0, 8K)
  int dstB = 8192 + wid * 4096;    // B region [8K, 24K)

  // frag reads: A mb = mi (all waves same A), B nb = wid*2 + ni
  int aRd = lane * 16;
  int bRd = 8192 + (wid * 2) * 2048 + lane * 16;

  f32x16 acc[4][2] = {};

  // prologue: stage tiles 0,1 (slots 0,1; 12 issues)
#pragma unroll
  for (int t = 0; t < 2; ++t) {
    uint8_t* buf = lds + t * 24576;
    long k0 = (long)t * 2048;
    gload_lds16(gA + k0, buf + dstA);
    gload_lds16(gA + k0 + 1024, buf + dstA + 1024);
    gload_lds16(gB0 + k0, buf + dstB);
    gload_lds16(gB0 + k0 + 1024, buf + dstB + 1024);
    gload_lds16(gB1 + k0, buf + dstB + 2048);
    gload_lds16(gB1 + k0 + 1024, buf + dstB + 3072);
  }
  asm volatile("s_waitcnt vmcnt(6)" ::: "memory");  // tile 0 landed
  barrier_raw();

#pragma unroll 1
  for (int tt = 0; tt < 30; tt += 3) {
    tile_step<6, true, 0>(tt, gA, gB0, gB1, dstA, dstB, lds, aRd, bRd, acc);
    tile_step<6, true, 1>(tt + 1, gA, gB0, gB1, dstA, dstB, lds, aRd, bRd, acc);
    tile_step<6, true, 2>(tt + 2, gA, gB0, gB1, dstA, dstB, lds, aRd, bRd, acc);
  }
  tile_step<0, false, 0>(30, gA, gB0, gB1, dstA, dstB, lds, aRd, bRd, acc);
  tile_step<-1, false, 1>(31, gA, gB0, gB1, dstA, dstB, lds, aRd, bRd, acc);

  // C/D 32x32 layout: col = lane&31, row = (reg&3) + 8*(reg>>2) + 4*(lane>>5)
  long row0 = (long)bm * 128 + ((lane >> 5) << 2);
  long col0 = (long)bn * 256 + wid * 64 + (lane & 31);
#pragma unroll
  for (int mi = 0; mi < 4; ++mi)
#pragma unroll
    for (int ni = 0; ni < 2; ++ni)
#pragma unroll
      for (int r = 0; r < 16; ++r) {
        long row = row0 + mi * 32 + (r & 3) + ((r >> 2) << 3);
        C[row * N_DIM + col0 + ni * 32] = acc[mi][ni][r];
      }
}

extern "C" void kernel_launch(void* const* d_in, const int* in_sizes, int n_in,
                              void* d_out, int out_size, void* d_ws, size_t ws_size,
                              hipStream_t stream) {
  const float* x = (const float*)d_in[0];
  const float* w = (const float*)d_in[1];
  float* out = (float*)d_out;

  uint8_t* x4 = (uint8_t*)d_ws;                     // 16 MB GEMM-ready A
  uint8_t* w4t = x4 + (size_t)M_DIM * (K_DIM / 2);  // 8 MB GEMM-ready W^T

  pack_x4_kernel<<<dim3(M_DIM / 32, 4), 256, 0, stream>>>(x, x4);
  pack_wt4_kernel<<<dim3(N_DIM / 64, K_DIM / 128), 256, 0, stream>>>(w, w4t);
  gemm_fp4_kernel<<<1024, 256, 0, stream>>>(x4, w4t, out);
}